// Round 3
// baseline (135.451 us; speedup 1.0000x reference)
//
#include <hip/hip_runtime.h>
#include <hip/hip_bf16.h>

#define B_    2
#define CIN   4
#define COUT  8
#define KK    4
#define DD    2
#define NN    224
#define FDIM  128
#define NH    218
#define NSUB  (NH*NH)      // 47524
#define NPERM 24
#define NROWS (B_*COUT*CIN)   // 64 softmax rows
#define NSUB4 (NSUB/4)        // 11881 float4s per row
#define CH4   512             // float4s per chunk (2048 floats)
#define MB    ((NSUB4 + CH4 - 1) / CH4)   // 24 chunk-blocks per row
#define OG    4               // o-groups; each thread handles COUT/OG = 2 o's

__device__ static constexpr int PERM[NPERM][4] = {
  {0,1,2,3},{0,1,3,2},{0,2,1,3},{0,2,3,1},{0,3,1,2},{0,3,2,1},
  {1,0,2,3},{1,0,3,2},{1,2,0,3},{1,2,3,0},{1,3,0,2},{1,3,2,0},
  {2,0,1,3},{2,0,3,1},{2,1,0,3},{2,1,3,0},{2,3,0,1},{2,3,1,0},
  {3,0,1,2},{3,0,2,1},{3,1,0,2},{3,1,2,0},{3,2,0,1},{3,2,1,0}
};

// one wave per (b,f): lanes split r, shuffle-reduce
__global__ __launch_bounds__(64) void hmean_kernel(const float* __restrict__ features,
                                                   float* __restrict__ out) {
  int bf = blockIdx.x;
  int b = bf / FDIM, f = bf - b * FDIM;
  int lane = threadIdx.x;
  const float* fb = features + (size_t)b * NN * FDIM + f;
  float acc = 0.f;
  for (int r = lane; r < NN; r += 64) {
    int w = 0;
#pragma unroll
    for (int a = 0; a < KK; ++a) {
      int i0 = r - a * DD;
      if (0 <= i0 && i0 < NH) w++;
    }
    acc += (float)w * fb[(size_t)r * FDIM];
  }
#pragma unroll
  for (int off = 32; off > 0; off >>= 1) acc += __shfl_down(acc, off, 64);
  if (lane == 0) out[bf] = acc * (2.0f / (float)NH);
}

// thread per (og,b,ci,s); handles o = og and og+4
__global__ __launch_bounds__(256) void sims_kernel(
    const float* __restrict__ graph, const float* __restrict__ types,
    const float* __restrict__ ksA, const float* __restrict__ krA,
    const float* __restrict__ kcA, float* __restrict__ simsOut)
{
  __shared__ float ls[COUT * CIN * 16];
  __shared__ float lr[COUT * CIN * 4];
  __shared__ float lc[COUT * CIN * 4];
  __shared__ float lK2[COUT * CIN];
  int t = threadIdx.x;
  for (int i = t; i < COUT * CIN * 16; i += 256) ls[i] = ksA[i];
  for (int i = t; i < COUT * CIN * 4; i += 256) { lr[i] = krA[i]; lc[i] = kcA[i]; }
  __syncthreads();
  if (t < COUT * CIN) {
    float k2 = 0.f;
#pragma unroll
    for (int u = 0; u < 16; ++u) k2 += ls[t * 16 + u] * ls[t * 16 + u];
#pragma unroll
    for (int u = 0; u < 4; ++u) k2 += lr[t * 4 + u] * lr[t * 4 + u] + lc[t * 4 + u] * lc[t * 4 + u];
    lK2[t] = k2;
  }
  __syncthreads();

  long long gid = (long long)blockIdx.x * 256 + t;
  if (gid >= (long long)OG * B_ * CIN * NSUB) return;
  int ogbci = (int)(gid / NSUB);
  int s     = (int)(gid - (long long)ogbci * NSUB);
  int og  = ogbci / (B_ * CIN);
  int bci = ogbci - og * (B_ * CIN);
  int b   = bci / CIN;
  int ci  = bci - b * CIN;
  int ii  = s / NH;
  int jj  = s - ii * NH;

  const float* gi = graph + ((size_t)b * CIN + ci) * NN * NN;
  const float* ti = types + ((size_t)b * CIN + ci) * NN;

  float subv[16], rtv[4], ctv[4];
  float G2 = 0.f, T2r = 0.f, T2c = 0.f;
#pragma unroll
  for (int a = 0; a < KK; ++a) {
    const float* row = gi + (size_t)(ii + a * DD) * NN + jj;
#pragma unroll
    for (int bb = 0; bb < KK; ++bb) {
      float v = row[bb * DD];
      subv[a * 4 + bb] = v;
      G2 += v * v;
    }
    float rv = ti[ii + a * DD];
    float cv = ti[jj + a * DD];
    rtv[a] = rv; ctv[a] = cv;
    T2r += rv * rv; T2c += cv * cv;
  }
  float base0 = G2 + T2r + T2c;

#pragma unroll
  for (int oo = 0; oo < COUT / OG; ++oo) {
    int o = og + oo * OG;
    int oc = o * CIN + ci;
    const float* pS = ls + oc * 16;
    const float* pR = lr + oc * 4;
    const float* pC = lc + oc * 4;
    float kS[16], kR[4], kC[4];
#pragma unroll
    for (int u = 0; u < 16; ++u) kS[u] = pS[u];
#pragma unroll
    for (int u = 0; u < 4; ++u) { kR[u] = pR[u]; kC[u] = pC[u]; }

    // C1[a][a'] = diag + row + col terms for mapping a->a'
    float C1[16];
#pragma unroll
    for (int a = 0; a < 4; ++a)
#pragma unroll
      for (int ap = 0; ap < 4; ++ap)
        C1[a * 4 + ap] = subv[a * 4 + a] * kS[ap * 4 + ap]
                       + rtv[a] * kR[ap] + ctv[a] * kC[ap];

    float maxcr = -3.4e38f;
#pragma unroll
    for (int p = 0; p < NPERM; ++p) {
      float cr = C1[0 * 4 + PERM[p][0]] + C1[1 * 4 + PERM[p][1]]
               + C1[2 * 4 + PERM[p][2]] + C1[3 * 4 + PERM[p][3]];
#pragma unroll
      for (int a = 0; a < 4; ++a)
#pragma unroll
        for (int bb = 0; bb < 4; ++bb)
          if (a != bb)
            cr += subv[a * 4 + bb] * kS[PERM[p][a] * 4 + PERM[p][bb]];
      maxcr = fmaxf(maxcr, cr);
    }
    float best = base0 + lK2[oc] - 2.0f * maxcr;
    simsOut[(((size_t)b * COUT + o) * CIN + ci) * NSUB + s] = best;
  }
}

// pass A: per (row, chunk) partial max + sumexp, float4
__global__ __launch_bounds__(256) void softmax_partial(const float* __restrict__ sims,
                                                       float* __restrict__ partial) {
  int blk = blockIdx.x;
  int row = blk / MB;
  int ch  = blk - row * MB;
  int base4 = ch * CH4;
  int n4 = NSUB4 - base4; if (n4 > CH4) n4 = CH4;
  const float4* rp = (const float4*)(sims + (size_t)row * NSUB) + base4;
  int t = threadIdx.x;

  float4 v[2]; int cnt = 0;
  for (int i = t; i < n4; i += 256) v[cnt++] = rp[i];

  __shared__ float red[256];
  float m = -3.4e38f;
  for (int u = 0; u < cnt; ++u)
    m = fmaxf(fmaxf(fmaxf(m, v[u].x), fmaxf(v[u].y, v[u].z)), v[u].w);
  red[t] = m; __syncthreads();
  for (int off = 128; off > 0; off >>= 1) {
    if (t < off) red[t] = fmaxf(red[t], red[t + off]);
    __syncthreads();
  }
  m = red[0]; __syncthreads();
  float l = 0.f;
  for (int u = 0; u < cnt; ++u)
    l += __expf(v[u].x - m) + __expf(v[u].y - m) + __expf(v[u].z - m) + __expf(v[u].w - m);
  red[t] = l; __syncthreads();
  for (int off = 128; off > 0; off >>= 1) {
    if (t < off) red[t] += red[t + off];
    __syncthreads();
  }
  if (t == 0) { partial[2 * blk] = m; partial[2 * blk + 1] = red[0]; }
}

// pass B: combine MB partials per row -> (M, 1/S)
__global__ __launch_bounds__(64) void softmax_combine(const float* __restrict__ partial,
                                                      float* __restrict__ stats) {
  int row = blockIdx.x;
  int t = threadIdx.x;
  float m = -3.4e38f, l = 0.f;
  if (t < MB) { m = partial[2 * (row * MB + t)]; l = partial[2 * (row * MB + t) + 1]; }
#pragma unroll
  for (int off = 32; off > 0; off >>= 1) m = fmaxf(m, __shfl_down(m, off, 64));
  m = __shfl(m, 0, 64);
  float contrib = (t < MB) ? l * __expf(partial[2 * (row * MB + t)] - m) : 0.f;
#pragma unroll
  for (int off = 32; off > 0; off >>= 1) contrib += __shfl_down(contrib, off, 64);
  if (t == 0) { stats[2 * row] = m; stats[2 * row + 1] = 1.0f / contrib; }
}

// pass C: rewrite in place, float4
__global__ __launch_bounds__(256) void softmax_final(float* __restrict__ sims,
                                                     const float* __restrict__ stats) {
  int blk = blockIdx.x;
  int row = blk / MB;
  int ch  = blk - row * MB;
  int base4 = ch * CH4;
  int n4 = NSUB4 - base4; if (n4 > CH4) n4 = CH4;
  float4* rp = (float4*)(sims + (size_t)row * NSUB) + base4;
  float M = stats[2 * row], invS = stats[2 * row + 1];
  const float scale = 1.0f / (float)NSUB;
  for (int i = threadIdx.x; i < n4; i += 256) {
    float4 v = rp[i];
    v.x = (1.0f - __expf(v.x - M) * invS) * scale;
    v.y = (1.0f - __expf(v.y - M) * invS) * scale;
    v.z = (1.0f - __expf(v.z - M) * invS) * scale;
    v.w = (1.0f - __expf(v.w - M) * invS) * scale;
    rp[i] = v;
  }
}

extern "C" void kernel_launch(void* const* d_in, const int* in_sizes, int n_in,
                              void* d_out, int out_size, void* d_ws, size_t ws_size,
                              hipStream_t stream) {
  const float* graph    = (const float*)d_in[0];
  const float* types    = (const float*)d_in[1];
  const float* features = (const float*)d_in[2];
  const float* ks       = (const float*)d_in[3];
  const float* kr       = (const float*)d_in[4];
  const float* kc       = (const float*)d_in[5];
  float* out  = (float*)d_out;
  float* sims = out + B_ * FDIM;

  float* partial = (float*)d_ws;                    // NROWS*MB*2 floats
  float* stats   = partial + NROWS * MB * 2;        // NROWS*2 floats

  hmean_kernel<<<B_ * FDIM, 64, 0, stream>>>(features, out);
  long long total = (long long)OG * B_ * CIN * NSUB;
  int nblk = (int)((total + 255) / 256);
  sims_kernel<<<nblk, 256, 0, stream>>>(graph, types, ks, kr, kc, sims);
  softmax_partial<<<NROWS * MB, 256, 0, stream>>>(sims, partial);
  softmax_combine<<<NROWS, 64, 0, stream>>>(partial, stats);
  softmax_final<<<NROWS * MB, 256, 0, stream>>>(sims, stats);
}

// Round 4
// 121.677 us; speedup vs baseline: 1.1132x; 1.1132x over previous
//
#include <hip/hip_runtime.h>
#include <hip/hip_bf16.h>

#define B_    2
#define CIN   4
#define COUT  8
#define KK    4
#define DD    2
#define NN    224
#define FDIM  128
#define NH    218
#define NSUB  (NH*NH)      // 47524
#define NPERM 24
#define NROWS (B_*COUT*CIN)   // 64 softmax rows
#define NSUB4 (NSUB/4)        // 11881 float4s per row
#define CH4   512             // float4s per chunk
#define MB    ((NSUB4 + CH4 - 1) / CH4)   // 24 chunk-blocks per row
#define OG    2               // o-groups; each thread handles COUT/OG = 4 o's

__device__ static constexpr int PERM[NPERM][4] = {
  {0,1,2,3},{0,1,3,2},{0,2,1,3},{0,2,3,1},{0,3,1,2},{0,3,2,1},
  {1,0,2,3},{1,0,3,2},{1,2,0,3},{1,2,3,0},{1,3,0,2},{1,3,2,0},
  {2,0,1,3},{2,0,3,1},{2,1,0,3},{2,1,3,0},{2,3,0,1},{2,3,1,0},
  {3,0,1,2},{3,0,2,1},{3,1,0,2},{3,1,2,0},{3,2,0,1},{3,2,1,0}
};

// one wave per (b,f): lanes split r, shuffle-reduce
__global__ __launch_bounds__(64) void hmean_kernel(const float* __restrict__ features,
                                                   float* __restrict__ out) {
  int bf = blockIdx.x;
  int b = bf / FDIM, f = bf - b * FDIM;
  int lane = threadIdx.x;
  const float* fb = features + (size_t)b * NN * FDIM + f;
  float acc = 0.f;
  for (int r = lane; r < NN; r += 64) {
    int w = 0;
#pragma unroll
    for (int a = 0; a < KK; ++a) {
      int i0 = r - a * DD;
      if (0 <= i0 && i0 < NH) w++;
    }
    acc += (float)w * fb[(size_t)r * FDIM];
  }
#pragma unroll
  for (int off = 32; off > 0; off >>= 1) acc += __shfl_down(acc, off, 64);
  if (lane == 0) out[bf] = acc * (2.0f / (float)NH);
}

// grid: (ceil(NSUB/256), B*CIN*OG). Each thread: one s, one (b,ci), COUT/OG o's.
__global__ __launch_bounds__(256) void sims_kernel(
    const float* __restrict__ graph, const float* __restrict__ types,
    const float* __restrict__ ksA, const float* __restrict__ krA,
    const float* __restrict__ kcA, float* __restrict__ simsOut)
{
  __shared__ float ls[COUT * CIN * 16];
  __shared__ float lr[COUT * CIN * 4];
  __shared__ float lc[COUT * CIN * 4];
  __shared__ float lK2[COUT * CIN];
  int t = threadIdx.x;
  for (int i = t; i < COUT * CIN * 16; i += 256) ls[i] = ksA[i];
  for (int i = t; i < COUT * CIN * 4; i += 256) { lr[i] = krA[i]; lc[i] = kcA[i]; }
  __syncthreads();
  if (t < COUT * CIN) {
    float k2 = 0.f;
#pragma unroll
    for (int u = 0; u < 16; ++u) k2 += ls[t * 16 + u] * ls[t * 16 + u];
#pragma unroll
    for (int u = 0; u < 4; ++u) k2 += lr[t * 4 + u] * lr[t * 4 + u] + lc[t * 4 + u] * lc[t * 4 + u];
    lK2[t] = k2;
  }
  __syncthreads();

  int s = blockIdx.x * 256 + t;
  if (s >= NSUB) return;             // no __syncthreads after this point
  int yi  = blockIdx.y;              // 0..B_*CIN*OG-1
  int og  = yi >> 3;                 // / (B_*CIN) == /8
  int bci = yi & 7;
  int b   = bci >> 2;
  int ci  = bci & 3;
  int ii  = s / NH;                  // magic-mul, constant divisor
  int jj  = s - ii * NH;

  const float* gi = graph + ((size_t)b * CIN + ci) * NN * NN;
  const float* ti = types + ((size_t)b * CIN + ci) * NN;

  float subv[16], rtv[4], ctv[4];
  float G2 = 0.f, T2r = 0.f, T2c = 0.f;
#pragma unroll
  for (int a = 0; a < KK; ++a) {
    const float* row = gi + (size_t)(ii + a * DD) * NN + jj;
#pragma unroll
    for (int bb = 0; bb < KK; ++bb) {
      float v = row[bb * DD];
      subv[a * 4 + bb] = v;
      G2 += v * v;
    }
    float rv = ti[ii + a * DD];
    float cv = ti[jj + a * DD];
    rtv[a] = rv; ctv[a] = cv;
    T2r += rv * rv; T2c += cv * cv;
  }
  float base0 = G2 + T2r + T2c;

#pragma unroll
  for (int oo = 0; oo < COUT / OG; ++oo) {
    int o = og * (COUT / OG) + oo;
    int oc = o * CIN + ci;
    const float* pS = ls + oc * 16;
    const float* pR = lr + oc * 4;
    const float* pC = lc + oc * 4;
    float kS[16], kR[4], kC[4];
#pragma unroll
    for (int u = 0; u < 16; ++u) kS[u] = pS[u];
#pragma unroll
    for (int u = 0; u < 4; ++u) { kR[u] = pR[u]; kC[u] = pC[u]; }

    // C1[a][a'] = subv_diag*kS_diag + row + col contribution for mapping a->a'
    float C1[16];
#pragma unroll
    for (int a = 0; a < 4; ++a)
#pragma unroll
      for (int ap = 0; ap < 4; ++ap)
        C1[a * 4 + ap] = subv[a * 4 + a] * kS[ap * 4 + ap]
                       + rtv[a] * kR[ap] + ctv[a] * kC[ap];

    float maxcr = -3.4e38f;
#pragma unroll
    for (int p = 0; p < NPERM; ++p) {
      const int p0 = PERM[p][0], p1 = PERM[p][1], p2 = PERM[p][2], p3 = PERM[p][3];
      float cr = C1[0 * 4 + p0] + C1[1 * 4 + p1] + C1[2 * 4 + p2] + C1[3 * 4 + p3];
      // 12 off-diagonal terms
      cr += subv[0*4+1] * kS[p0*4+p1];
      cr += subv[0*4+2] * kS[p0*4+p2];
      cr += subv[0*4+3] * kS[p0*4+p3];
      cr += subv[1*4+0] * kS[p1*4+p0];
      cr += subv[1*4+2] * kS[p1*4+p2];
      cr += subv[1*4+3] * kS[p1*4+p3];
      cr += subv[2*4+0] * kS[p2*4+p0];
      cr += subv[2*4+1] * kS[p2*4+p1];
      cr += subv[2*4+3] * kS[p2*4+p3];
      cr += subv[3*4+0] * kS[p3*4+p0];
      cr += subv[3*4+1] * kS[p3*4+p1];
      cr += subv[3*4+2] * kS[p3*4+p2];
      maxcr = fmaxf(maxcr, cr);
    }
    float best = base0 + lK2[oc] - 2.0f * maxcr;
    simsOut[(((size_t)b * COUT + o) * CIN + ci) * NSUB + s] = best;
  }
}

// pass A: per (row, chunk) partial max + sumexp, float4
__global__ __launch_bounds__(256) void softmax_partial(const float* __restrict__ sims,
                                                       float* __restrict__ partial) {
  int blk = blockIdx.x;
  int row = blk / MB;
  int ch  = blk - row * MB;
  int base4 = ch * CH4;
  int n4 = NSUB4 - base4; if (n4 > CH4) n4 = CH4;
  const float4* rp = (const float4*)(sims + (size_t)row * NSUB) + base4;
  int t = threadIdx.x;

  float4 v[2]; int cnt = 0;
  for (int i = t; i < n4; i += 256) v[cnt++] = rp[i];

  __shared__ float red[256];
  float m = -3.4e38f;
  for (int u = 0; u < cnt; ++u)
    m = fmaxf(fmaxf(fmaxf(m, v[u].x), fmaxf(v[u].y, v[u].z)), v[u].w);
  red[t] = m; __syncthreads();
  for (int off = 128; off > 0; off >>= 1) {
    if (t < off) red[t] = fmaxf(red[t], red[t + off]);
    __syncthreads();
  }
  m = red[0]; __syncthreads();
  float l = 0.f;
  for (int u = 0; u < cnt; ++u)
    l += __expf(v[u].x - m) + __expf(v[u].y - m) + __expf(v[u].z - m) + __expf(v[u].w - m);
  red[t] = l; __syncthreads();
  for (int off = 128; off > 0; off >>= 1) {
    if (t < off) red[t] += red[t + off];
    __syncthreads();
  }
  if (t == 0) { partial[2 * blk] = m; partial[2 * blk + 1] = red[0]; }
}

// pass B: combine MB partials per row -> (M, 1/S)
__global__ __launch_bounds__(64) void softmax_combine(const float* __restrict__ partial,
                                                      float* __restrict__ stats) {
  int row = blockIdx.x;
  int t = threadIdx.x;
  float m = -3.4e38f, l = 0.f;
  if (t < MB) { m = partial[2 * (row * MB + t)]; l = partial[2 * (row * MB + t) + 1]; }
#pragma unroll
  for (int off = 32; off > 0; off >>= 1) m = fmaxf(m, __shfl_down(m, off, 64));
  m = __shfl(m, 0, 64);
  float contrib = (t < MB) ? l * __expf(partial[2 * (row * MB + t)] - m) : 0.f;
#pragma unroll
  for (int off = 32; off > 0; off >>= 1) contrib += __shfl_down(contrib, off, 64);
  if (t == 0) { stats[2 * row] = m; stats[2 * row + 1] = 1.0f / contrib; }
}

// pass C: rewrite in place, float4
__global__ __launch_bounds__(256) void softmax_final(float* __restrict__ sims,
                                                     const float* __restrict__ stats) {
  int blk = blockIdx.x;
  int row = blk / MB;
  int ch  = blk - row * MB;
  int base4 = ch * CH4;
  int n4 = NSUB4 - base4; if (n4 > CH4) n4 = CH4;
  float4* rp = (float4*)(sims + (size_t)row * NSUB) + base4;
  float M = stats[2 * row], invS = stats[2 * row + 1];
  const float scale = 1.0f / (float)NSUB;
  for (int i = threadIdx.x; i < n4; i += 256) {
    float4 v = rp[i];
    v.x = (1.0f - __expf(v.x - M) * invS) * scale;
    v.y = (1.0f - __expf(v.y - M) * invS) * scale;
    v.z = (1.0f - __expf(v.z - M) * invS) * scale;
    v.w = (1.0f - __expf(v.w - M) * invS) * scale;
    rp[i] = v;
  }
}

extern "C" void kernel_launch(void* const* d_in, const int* in_sizes, int n_in,
                              void* d_out, int out_size, void* d_ws, size_t ws_size,
                              hipStream_t stream) {
  const float* graph    = (const float*)d_in[0];
  const float* types    = (const float*)d_in[1];
  const float* features = (const float*)d_in[2];
  const float* ks       = (const float*)d_in[3];
  const float* kr       = (const float*)d_in[4];
  const float* kc       = (const float*)d_in[5];
  float* out  = (float*)d_out;
  float* sims = out + B_ * FDIM;

  float* partial = (float*)d_ws;                    // NROWS*MB*2 floats
  float* stats   = partial + NROWS * MB * 2;        // NROWS*2 floats

  hmean_kernel<<<B_ * FDIM, 64, 0, stream>>>(features, out);
  dim3 sgrid((NSUB + 255) / 256, B_ * CIN * OG);
  sims_kernel<<<sgrid, 256, 0, stream>>>(graph, types, ks, kr, kc, sims);
  softmax_partial<<<NROWS * MB, 256, 0, stream>>>(sims, partial);
  softmax_combine<<<NROWS, 64, 0, stream>>>(partial, stats);
  softmax_final<<<NROWS * MB, 256, 0, stream>>>(sims, stats);
}